// Round 20
// baseline (93.823 us; speedup 1.0000x reference)
//
#include <hip/hip_runtime.h>
#include <hip/hip_bf16.h>
#include <hip/hip_fp8.h>

#define S_ 1024
#define D_ 128
#define V_ 100000
#define VSTRIPS_ 3136   // 32-row v-strips; 3125 valid (=100000), 11 zero pads
#define NPHASE_ 64      // 64 phases x 49 strips = 3136
#define N_ 4096
#define PADROWS_ 352.0f

typedef __attribute__((ext_vector_type(4))) float f32x4;
typedef __attribute__((ext_vector_type(4))) int   i32x4;
typedef __attribute__((ext_vector_type(8))) int   i32x8;

#define LOG2E_ 1.4426950408889634f
#define LN2_   0.6931471805599453f

__device__ __forceinline__ float exp2_fast(float x) {
#if __has_builtin(__builtin_amdgcn_exp2f)
    return __builtin_amdgcn_exp2f(x);
#else
    return exp2f(x);
#endif
}

__device__ __forceinline__ unsigned char to_fp8(float x) {
    __hip_fp8_e4m3 t(x);
    return (unsigned char)t.__x;
}
__device__ __forceinline__ float from_fp8(unsigned char b) {
    __hip_fp8_e4m3 t; t.__x = (__hip_fp8_storage_t)b;
    return (float)t;
}

// ---- kernel 1: prep = knorm (fragment-major fp8 Kn) + qnorm (row-major fp8 Qn) ----
// Kn strip layout (CONTIGUOUS 32B per MFMA lane): strip = 4KB,
//   element (r local, k): addr = (r>>4)*2048 + ((k>>5)*16 + (r&15))*32 + (k&31)
__global__ void prep_kernel(const float* __restrict__ K, const float* __restrict__ Q,
                            const int* __restrict__ loc,
                            char* __restrict__ Kn, char* __restrict__ Qn,
                            float* __restrict__ Ssum) {
    __shared__ char sm[4096];
    const int bid = blockIdx.x;
    const int tid = threadIdx.x;
    const int lane = tid & 63;
    const int wvv = tid >> 6;
    if (bid < VSTRIPS_) {                      // ---- K strip ----
        char* dst = Kn + (size_t)bid * 4096;
        if (bid >= 3125) {                     // zero pad strip: fp8 0x00 = 0.0
            *(f32x4*)(dst + tid * 16) = (f32x4){0.f, 0.f, 0.f, 0.f};
            return;
        }
        #pragma unroll
        for (int i = 0; i < 8; ++i) {
            int r = wvv * 8 + i;
            float2 v = ((const float2*)(K + ((size_t)bid * 32 + r) * D_))[lane];
            float ss = v.x * v.x + v.y * v.y;
            #pragma unroll
            for (int off = 32; off; off >>= 1) ss += __shfl_xor(ss, off);
            float rn = rsqrtf(ss);
            unsigned short pk = (unsigned short)to_fp8(v.x * rn)
                              | ((unsigned short)to_fp8(v.y * rn) << 8);
            int addr = ((r >> 4) << 11) + (((lane >> 4) * 16 + (r & 15)) << 5)
                     + ((lane & 15) << 1);
            *(unsigned short*)(sm + addr) = pk;
        }
        __syncthreads();
        *(f32x4*)(dst + tid * 16) = *(const f32x4*)(sm + tid * 16);
    } else {                                   // ---- Q rows (4 per block) ----
        int w = (bid - VSTRIPS_) * 4 + wvv;
        if (lane == 0) Ssum[w] = 0.f;
        int b = loc[2 * w], s = loc[2 * w + 1];
        float2 v = ((const float2*)(Q + ((size_t)b * S_ + (size_t)s) * D_))[lane];
        float ss = v.x * v.x + v.y * v.y;
        #pragma unroll
        for (int off = 32; off; off >>= 1) ss += __shfl_xor(ss, off);
        float rn = rsqrtf(ss) * LOG2E_;        // exp2 domain
        unsigned short pk = (unsigned short)to_fp8(v.x * rn)
                          | ((unsigned short)to_fp8(v.y * rn) << 8);
        *(unsigned short*)(Qn + (size_t)w * 128 + 2 * lane) = pk;
    }
}

// ---- kernel 2: main -- WAVE-SPECIALIZED producer/consumer (m114: separate
// MFMA-only and VALU-only waves on a CU overlap fully, time = max not sum).
// 512 threads: waves 0-3 = producers (loads + MFMA -> logits into LDS),
// waves 4-7 = consumers (ds_read + exp2 + accumulate). Double-buffered
// 2 x 32KB LDS; ONE __syncthreads per strip swaps roles of the buffers.
// Producer p handles q-rows [qb*256 + p*64, +64) x 32v (m=4, nn=2, fp8 K=128).
__global__ __launch_bounds__(512, 1) void ce_main(
    const char* __restrict__ Qn,
    const char* __restrict__ Kn,
    float* __restrict__ Ssum)
{
    __shared__ char lbuf[65536];     // [2][4 producers][8 frag][64 lanes][16B]

    const int tid  = threadIdx.x;
    const int lane = tid & 63;
    const int wv   = tid >> 6;       // 0..7
    const int p    = wv & 3;         // producer/consumer pair id
    const int r0   = lane & 15;
    const int hi   = lane >> 4;      // 0..3

    // grid (16,64): XCD owns 8 whole phase-groups (all 16 q-blocks of each)
    const int fid   = blockIdx.y * 16 + blockIdx.x;
    const int xcd   = fid & 7;
    const int idx   = fid >> 3;              // 0..127
    const int phase = xcd * 8 + (idx >> 4);  // 0..63
    const int qb    = idx & 15;              // 0..15 (256 q-rows each)

    const int loff = (p << 13) + (lane << 4);   // within a 32KB buffer half

    if (wv < 4) {
        // ================= PRODUCER: loads + MFMA only =================
        i32x8 afr[4];
        {
            const char* qsrc = Qn + ((size_t)qb * 256 + p * 64 + r0) * 128 + (hi << 5);
            #pragma unroll
            for (int m = 0; m < 4; ++m)
                afr[m] = *(const i32x8*)(qsrc + m * 2048);
        }
        const char* kvbase = Kn + (size_t)phase * 4096 + (lane << 5);
        const f32x4 fz = {0.f, 0.f, 0.f, 0.f};
        f32x4 acc[4][2];
        i32x8 RA0, RA1, RB0, RB1;

#define LOADSET(B0, B1, j) do {                                              \
        const char* pp = kvbase + (size_t)(j) * (4096 * NPHASE_);            \
        B0 = *(const i32x8*)(pp);                                            \
        B1 = *(const i32x8*)(pp + 2048);                                     \
    } while (0)

#define COMPUTE(B0, B1) do {                                                 \
        _Pragma("unroll")                                                    \
        for (int m = 0; m < 4; ++m) {                                        \
            acc[m][0] = __builtin_amdgcn_mfma_scale_f32_16x16x128_f8f6f4(    \
                afr[m], B0, fz, 0, 0, 0, 127, 0, 127);                       \
            acc[m][1] = __builtin_amdgcn_mfma_scale_f32_16x16x128_f8f6f4(    \
                afr[m], B1, fz, 0, 0, 0, 127, 0, 127);                       \
        }                                                                    \
    } while (0)

#define WRITEACC(OFF) do {                                                   \
        _Pragma("unroll")                                                    \
        for (int m = 0; m < 4; ++m)                                          \
            _Pragma("unroll")                                                \
            for (int nn = 0; nn < 2; ++nn)                                   \
                *(f32x4*)(lbuf + (OFF) + loff + ((m * 2 + nn) << 10)) = acc[m][nn]; \
    } while (0)

        LOADSET(RA0, RA1, 0);
        #pragma unroll 1
        for (int j = 0; j < 48; j += 2) {
            LOADSET(RB0, RB1, j + 1);
            COMPUTE(RA0, RA1);           // strip j
            WRITEACC(0);
            __syncthreads();
            LOADSET(RA0, RA1, j + 2);    // j+2 <= 48: valid
            COMPUTE(RB0, RB1);           // strip j+1
            WRITEACC(32768);
            __syncthreads();
        }
        COMPUTE(RA0, RA1);               // strip 48
        WRITEACC(0);
        __syncthreads();
#undef LOADSET
#undef COMPUTE
#undef WRITEACC
    } else {
        // ================= CONSUMER: ds_read + exp2 only =================
        float psum[4][4];
        #pragma unroll
        for (int m = 0; m < 4; ++m)
            #pragma unroll
            for (int q = 0; q < 4; ++q) psum[m][q] = 0.f;

#define READEXP(OFF) do {                                                    \
        _Pragma("unroll")                                                    \
        for (int m = 0; m < 4; ++m) {                                        \
            f32x4 v0 = *(const f32x4*)(lbuf + (OFF) + loff + ((m * 2) << 10));       \
            f32x4 v1 = *(const f32x4*)(lbuf + (OFF) + loff + ((m * 2 + 1) << 10));   \
            _Pragma("unroll")                                                \
            for (int q = 0; q < 4; ++q)                                      \
                psum[m][q] += exp2_fast(v0[q]) + exp2_fast(v1[q]);           \
        }                                                                    \
    } while (0)

        #pragma unroll 1
        for (int j = 0; j < 48; j += 2) {
            __syncthreads();             // buf0 = strip j ready
            READEXP(0);
            __syncthreads();             // buf1 = strip j+1 ready
            READEXP(32768);
        }
        __syncthreads();                 // buf0 = strip 48 ready
        READEXP(0);
#undef READEXP

        // reduce over 16 lanes (same q-rows, different v-cols), then atomics
        #pragma unroll
        for (int m = 0; m < 4; ++m) {
            #pragma unroll
            for (int q = 0; q < 4; ++q) {
                float v = psum[m][q];
                v += __shfl_xor(v, 1);
                v += __shfl_xor(v, 2);
                v += __shfl_xor(v, 4);
                v += __shfl_xor(v, 8);
                if (r0 == 0) {
                    int row = qb * 256 + p * 64 + m * 16 + hi * 4 + q;
                    atomicAdd(&Ssum[row], v);
                }
            }
        }
    }
}

// ---- kernel 3: per-row term = log(S - PADROWS) - true_logit ----
// Kn element (r=lab&31, k=2*lane): addr = (lab>>5)*4096 + ((lab>>4)&1)*2048
//   + ((lane>>4)*16 + (lab&15))*32 + 2*(lane&15)
__global__ void term_kernel(const char* __restrict__ Qn,
                            const char* __restrict__ Kn,
                            const int* __restrict__ labels,
                            const float* __restrict__ Ssum,
                            float* __restrict__ T) {
    int w = (blockIdx.x * blockDim.x + threadIdx.x) >> 6;
    int lane = threadIdx.x & 63;
    if (w >= N_) return;
    int lab = labels[w];
    const unsigned char* qp = (const unsigned char*)(Qn + (size_t)w * 128 + 2 * lane);
    const unsigned char* kp = (const unsigned char*)(Kn
                      + ((size_t)(lab >> 5)) * 4096 + (((lab >> 4) & 1) << 11)
                      + (((lane >> 4) * 16 + (lab & 15)) << 5) + ((lane & 15) << 1));
    float d = from_fp8(qp[0]) * from_fp8(kp[0])
            + from_fp8(qp[1]) * from_fp8(kp[1]);
    #pragma unroll
    for (int off = 32; off; off >>= 1) d += __shfl_xor(d, off);
    if (lane == 0) T[w] = logf(Ssum[w] - PADROWS_) - d * LN2_;
}

// ---- kernel 4: mean over N ----
__global__ void reduce_kernel(const float* __restrict__ T, float* __restrict__ out) {
    __shared__ float sm[4];
    float s = 0.f;
    for (int i = threadIdx.x; i < N_; i += 256) s += T[i];
    #pragma unroll
    for (int off = 32; off; off >>= 1) s += __shfl_xor(s, off);
    if ((threadIdx.x & 63) == 0) sm[threadIdx.x >> 6] = s;
    __syncthreads();
    if (threadIdx.x == 0) out[0] = (sm[0] + sm[1] + sm[2] + sm[3]) * (1.0f / (float)N_);
}

extern "C" void kernel_launch(void* const* d_in, const int* in_sizes, int n_in,
                              void* d_out, int out_size, void* d_ws, size_t ws_size,
                              hipStream_t stream) {
    (void)in_sizes; (void)n_in; (void)out_size; (void)ws_size;
    const float* Q   = (const float*)d_in[0];
    const float* K   = (const float*)d_in[1];
    const int* loc   = (const int*)d_in[2];
    const int* labels= (const int*)d_in[3];
    float* out = (float*)d_out;

    char* ws = (char*)d_ws;
    char* Kn    = ws;                                   // 3136*4096 = 12,845,056 B
    char* Qn    = ws + 12845056;                        // N_*128    =     524,288 B
    float* Ssum = (float*)(ws + 12845056 + 524288);     // N_*4
    float* T    = Ssum + N_;                            // N_*4

    prep_kernel<<<VSTRIPS_ + N_ / 4, 256, 0, stream>>>(K, Q, loc, Kn, Qn, Ssum);
    ce_main<<<dim3(16, NPHASE_), 512, 0, stream>>>(Qn, Kn, Ssum);
    term_kernel<<<N_ / 4, 256, 0, stream>>>(Qn, Kn, labels, Ssum, T);
    reduce_kernel<<<1, 256, 0, stream>>>(T, out);
}